// Round 11
// baseline (105.883 us; speedup 1.0000x reference)
//
#include <hip/hip_runtime.h>

#define V_ 25000
#define F_ 8192
#define E_ (3 * F_) // 24576

constexpr int CAP  = 101;      // per-edge cap; face clip at 100 makes this lossless
constexpr int GD   = 8;        // grid cells per axis (unit cells over [-4,4), clamped)
constexpr int NC   = GD*GD*GD; // 512 cells
constexpr int CAPC = 6144;     // per-cell list capacity (center cell ~4400 expected)

// ws layout:
//   C4        float4[E_]        @ 0           (cx,cy,cz, __int_as_float(cell))
//   cellList  float4[NC*CAPC]   @ 393,216     (50,331,648 B)
//   cellCount int[NC]           @ 50,724,864  (2,048 B — the only memset)
//   cnt       int[E_]           @ 50,726,912  (98,304 B — fully overwritten)
constexpr size_t OFF_LIST = 393216;
constexpr size_t OFF_CCNT = 50724864;
constexpr size_t OFF_CNT  = 50726912;

__device__ __forceinline__ int cell_coord(float c)
{
    // monotone map -> clamped cell index; any pair with |dc|<1 stays within +-1 cell
    return min(GD-1, max(0, (int)floorf(c) + GD/2));
}

// 96 blocks x 256: centroid + cell, LDS-rank counting-append into per-cell lists.
__global__ __launch_bounds__(256) void build_kernel(
    const float* __restrict__ vertices, const int* __restrict__ faces,
    float4* __restrict__ C4, float4* __restrict__ cellList,
    int* __restrict__ cellCount)
{
    __shared__ int lh[NC];
    __shared__ int lbase[NC];
    for (int i = threadIdx.x; i < NC; i += 256) lh[i] = 0;
    __syncthreads();

    const int e = blockIdx.x * 256 + threadIdx.x;
    int f, i0, i1;
    if (e < F_)        { f = e;        i0 = 0; i1 = 1; }
    else if (e < 2*F_) { f = e - F_;   i0 = 1; i1 = 2; }
    else               { f = e - 2*F_; i0 = 2; i1 = 0; }
    int a = faces[f*3 + i0];
    int b = faces[f*3 + i1];
    float cx = 0.5f*(vertices[a*3+0] + vertices[b*3+0]);
    float cy = 0.5f*(vertices[a*3+1] + vertices[b*3+1]);
    float cz = 0.5f*(vertices[a*3+2] + vertices[b*3+2]);
    int cell = (cell_coord(cz)*GD + cell_coord(cy))*GD + cell_coord(cx);
    int rank = atomicAdd(&lh[cell], 1);
    __syncthreads();
    for (int i = threadIdx.x; i < NC; i += 256) {
        int c = lh[i];
        if (c) lbase[i] = atomicAdd(&cellCount[i], c);
    }
    __syncthreads();
    C4[e] = make_float4(cx, cy, cz, __int_as_float(cell));
    cellList[(size_t)cell * CAPC + lbase[cell] + rank] = make_float4(cx, cy, cz, 0.f);
}

// One wave per edge. All 27 neighbor counts loaded in ONE batched cluster;
// own cell scanned first with 1-deep chunk prefetch (90% cap-exit here);
// remaining 26 cells in two batches of 13 with all first-chunks prefetched
// in one cluster (survivors are low-density edges that scan everything
// anyway, so the batch is not wasted). No cross-wave atomics.
__global__ __launch_bounds__(256) void count_kernel(
    const float4* __restrict__ C4, const float4* __restrict__ cellList,
    const int* __restrict__ cellCount, int* __restrict__ cnt)
{
    const int wave = threadIdx.x >> 6;
    const int lane = threadIdx.x & 63;
    const int e = blockIdx.x * 4 + wave;

    float4 s = C4[e];                          // wave-uniform broadcast
    const float ex = s.x, ey = s.y, ez = s.z;
    const int   cell = __float_as_int(s.w);
    const int ix = cell & 7, iy = (cell >> 3) & 7, iz = cell >> 6;
    const float d2t = (1.0f + 1e-6f) * (1.0f + 1e-6f);

    // own cell first, then own plane, then z=-1 plane, then z=+1 plane
    constexpr int DXT[27] = {0, -1,1, 0, 0,-1, 1,-1, 1,
                                 0,-1, 1, 0, 0,-1, 1,-1, 1,
                                 0,-1, 1, 0, 0,-1, 1,-1, 1};
    constexpr int DYT[27] = {0,  0,0,-1, 1,-1,-1, 1, 1,
                                 0, 0, 0,-1, 1,-1,-1, 1, 1,
                                 0, 0, 0,-1, 1,-1,-1, 1, 1};
    constexpr int DZT[27] = {0,  0,0, 0, 0, 0, 0, 0, 0,
                                -1,-1,-1,-1,-1,-1,-1,-1,-1,
                                 1, 1, 1, 1, 1, 1, 1, 1, 1};

    // ---- batched neighbor-count loads (27 independent, ~1 latency hop) ----
    int nArr[27];
#pragma unroll
    for (int q = 0; q < 27; ++q) {
        int x = ix + DXT[q], y = iy + DYT[q], z = iz + DZT[q];
        bool ok = ((unsigned)x < (unsigned)GD) & ((unsigned)y < (unsigned)GD)
                & ((unsigned)z < (unsigned)GD);
        int nc = cell + DZT[q]*64 + DYT[q]*8 + DXT[q];   // constant offset per q
        // speculative OOB (+-~300B around cellCount) stays inside ws — safe
        nArr[q] = ok ? cellCount[nc] : 0;
    }

    int count = 0;

    // ---- own cell: 1-deep chunk prefetch ----
    {
        const int n = nArr[0];                 // >=1 (contains own edge)
        const float4* __restrict__ L = cellList + (size_t)cell * CAPC;
        float4 cur = L[min(lane, n-1)];
        int base = 0;
        for (;;) {
            int nb = base + 64;
            bool more = nb < n;
            float4 nxt;
            if (more) nxt = L[min(nb + lane, n-1)];   // issued before ballot
            float dx = ex - cur.x, dy = ey - cur.y, dz = ez - cur.z;
            float d2 = dx*dx + dy*dy + dz*dz;
            bool c = (base + lane < n) && (d2 < d2t);
            count += __popcll(__ballot(c));
            if (count >= CAP) goto done;       // wave-uniform
            if (!more) break;
            cur = nxt; base = nb;
        }
    }

    // ---- remaining 26 cells in two batches of 13 ----
#pragma unroll
    for (int half = 0; half < 2; ++half) {
        const int q0 = 1 + half * 13;
        float4 pf[13];
#pragma unroll
        for (int j = 0; j < 13; ++j) {         // 13 first-chunk loads, one cluster
            const int q = q0 + j;
            const int n = nArr[q];
            if (n > 0) {
                const float4* __restrict__ L =
                    cellList + (size_t)(cell + DZT[q]*64 + DYT[q]*8 + DXT[q]) * CAPC;
                pf[j] = L[min(lane, n-1)];
            }
        }
#pragma unroll
        for (int j = 0; j < 13; ++j) {
            const int q = q0 + j;
            const int n = nArr[q];
            if (n <= 0) continue;
            const float4* __restrict__ L =
                cellList + (size_t)(cell + DZT[q]*64 + DYT[q]*8 + DXT[q]) * CAPC;
            {   // chunk 0 from the prefetched batch
                float dx = ex - pf[j].x, dy = ey - pf[j].y, dz = ez - pf[j].z;
                float d2 = dx*dx + dy*dy + dz*dz;
                bool c = (lane < n) && (d2 < d2t);
                count += __popcll(__ballot(c));
                if (count >= CAP) goto done;
            }
            if (n > 64) {                      // rare path: dense neighbor cell
                float4 cur = L[min(64 + lane, n-1)];
                int base = 64;
                for (;;) {
                    int nb = base + 64;
                    bool more = nb < n;
                    float4 nxt;
                    if (more) nxt = L[min(nb + lane, n-1)];
                    float dx = ex - cur.x, dy = ey - cur.y, dz = ez - cur.z;
                    float d2 = dx*dx + dy*dy + dz*dz;
                    bool c = (base + lane < n) && (d2 < d2t);
                    count += __popcll(__ballot(c));
                    if (count >= CAP) goto done;
                    if (!more) break;
                    cur = nxt; base = nb;
                }
            }
        }
    }
done:
    if (lane == 0) cnt[e] = count;
}

__global__ __launch_bounds__(1024) void reduce_kernel(
    const int* __restrict__ cnt, const float* __restrict__ probs,
    float* __restrict__ out)
{
    float local = 0.0f;
    for (int f = threadIdx.x; f < F_; f += 1024) {
        // face f's edges in the concatenated [(0,1),(1,2),(2,0)] layout
        float c = (float)(cnt[f] + cnt[F_ + f] + cnt[2*F_ + f]);
        c = fminf(fmaxf(c, 0.0f), 100.0f);
        local += probs[f] * c;
    }
#pragma unroll
    for (int off = 32; off > 0; off >>= 1)
        local += __shfl_down(local, off, 64);
    __shared__ float wsum[16];
    if ((threadIdx.x & 63) == 0) wsum[threadIdx.x >> 6] = local;
    __syncthreads();
    if (threadIdx.x == 0) {
        float t = 0.0f;
#pragma unroll
        for (int w = 0; w < 16; w++) t += wsum[w];
        out[0] = t / (float)F_;
    }
}

extern "C" void kernel_launch(void* const* d_in, const int* in_sizes, int n_in,
                              void* d_out, int out_size, void* d_ws, size_t ws_size,
                              hipStream_t stream)
{
    const float* vertices = (const float*)d_in[0];
    const int*   faces    = (const int*)d_in[1];   // int64 in reference -> int32 on device
    const float* probs    = (const float*)d_in[2];
    float* out = (float*)d_out;

    char* ws = (char*)d_ws;
    float4* C4        = (float4*)ws;
    float4* cellList  = (float4*)(ws + OFF_LIST);
    int*    cellCount = (int*)(ws + OFF_CCNT);
    int*    cnt       = (int*)(ws + OFF_CNT);

    hipMemsetAsync(cellCount, 0, NC * sizeof(int), stream);
    hipLaunchKernelGGL(build_kernel, dim3(E_ / 256), dim3(256), 0, stream,
                       vertices, faces, C4, cellList, cellCount);
    hipLaunchKernelGGL(count_kernel, dim3(E_ / 4), dim3(256), 0, stream,
                       C4, cellList, cellCount, cnt);
    hipLaunchKernelGGL(reduce_kernel, dim3(1), dim3(1024), 0, stream,
                       cnt, probs, out);
}

// Round 12
// 88.891 us; speedup vs baseline: 1.1912x; 1.1912x over previous
//
#include <hip/hip_runtime.h>

#define V_ 25000
#define F_ 8192
#define E_ (3 * F_) // 24576

constexpr int CAP  = 101;      // per-edge cap; face clip at 100 makes this lossless
constexpr int GD   = 8;        // grid cells per axis (unit cells over [-4,4), clamped)
constexpr int NC   = GD*GD*GD; // 512 cells
constexpr int CAPC = 6144;     // per-cell list capacity (center cell ~4400 expected)
constexpr int FLATCAP = 384;   // max flat chunks on the pipelined path

// ws layout:
//   C4        float4[E_]        @ 0           (cx,cy,cz, __int_as_float(cell))
//   cellList  float4[NC*CAPC]   @ 393,216     (50,331,648 B)
//   cellCount int[NC]           @ 50,724,864  (2,048 B — the only memset)
//   cnt       int[E_]           @ 50,726,912  (98,304 B — fully overwritten)
constexpr size_t OFF_LIST = 393216;
constexpr size_t OFF_CCNT = 50724864;
constexpr size_t OFF_CNT  = 50726912;

// 26 neighbor patterns in DESCENDING center-ward score (a+b+c); applied as
// offset = pattern * (dirx,diry,dirz). Bijective onto {-1,0,1}^3 \ {0}.
__device__ const int PPAT[26][3] = {
    { 1, 1, 1},
    { 1, 1, 0},{ 1, 0, 1},{ 0, 1, 1},
    { 1, 0, 0},{ 0, 1, 0},{ 0, 0, 1},{ 1, 1,-1},{ 1,-1, 1},{-1, 1, 1},
    { 1,-1, 0},{ 1, 0,-1},{ 0, 1,-1},{-1, 1, 0},{-1, 0, 1},{ 0,-1, 1},
    {-1, 0, 0},{ 0,-1, 0},{ 0, 0,-1},{-1,-1, 1},{-1, 1,-1},{ 1,-1,-1},
    {-1,-1, 0},{-1, 0,-1},{ 0,-1,-1},
    {-1,-1,-1}
};

__device__ __forceinline__ int cell_coord(float c)
{
    return min(GD-1, max(0, (int)floorf(c) + GD/2));
}

// 96 blocks x 256: centroid + cell, LDS-rank counting-append into per-cell lists.
__global__ __launch_bounds__(256) void build_kernel(
    const float* __restrict__ vertices, const int* __restrict__ faces,
    float4* __restrict__ C4, float4* __restrict__ cellList,
    int* __restrict__ cellCount)
{
    __shared__ int lh[NC];
    __shared__ int lbase[NC];
    for (int i = threadIdx.x; i < NC; i += 256) lh[i] = 0;
    __syncthreads();

    const int e = blockIdx.x * 256 + threadIdx.x;
    int f, i0, i1;
    if (e < F_)        { f = e;        i0 = 0; i1 = 1; }
    else if (e < 2*F_) { f = e - F_;   i0 = 1; i1 = 2; }
    else               { f = e - 2*F_; i0 = 2; i1 = 0; }
    int a = faces[f*3 + i0];
    int b = faces[f*3 + i1];
    float cx = 0.5f*(vertices[a*3+0] + vertices[b*3+0]);
    float cy = 0.5f*(vertices[a*3+1] + vertices[b*3+1]);
    float cz = 0.5f*(vertices[a*3+2] + vertices[b*3+2]);
    int cell = (cell_coord(cz)*GD + cell_coord(cy))*GD + cell_coord(cx);
    int rank = atomicAdd(&lh[cell], 1);
    __syncthreads();
    for (int i = threadIdx.x; i < NC; i += 256) {
        int c = lh[i];
        if (c) lbase[i] = atomicAdd(&cellCount[i], c);
    }
    __syncthreads();
    C4[e] = make_float4(cx, cy, cz, __int_as_float(cell));
    cellList[(size_t)cell * CAPC + lbase[cell] + rank] = make_float4(cx, cy, cz, 0.f);
}

// One wave per edge. Own cell first (mass cap-exits here). Survivors build a
// per-wave flat chunk list over the 26 pattern cells (densest-first order)
// and scan it with a depth-4 load pipeline. All loads predicate-guarded.
__global__ __launch_bounds__(256) void count_kernel(
    const float4* __restrict__ C4, const float4* __restrict__ cellList,
    const int* __restrict__ cellCount, int* __restrict__ cnt)
{
    __shared__ unsigned flatLDS[4][FLATCAP + 16];
    const int wave = threadIdx.x >> 6;
    const int lane = threadIdx.x & 63;
    const int e = blockIdx.x * 4 + wave;

    float4 s = C4[e];                          // wave-uniform broadcast
    const float ex = s.x, ey = s.y, ez = s.z;
    const int   cell = __float_as_int(s.w);
    const int ix = cell & 7, iy = (cell >> 3) & 7, iz = cell >> 6;
    const float d2t = (1.0f + 1e-6f) * (1.0f + 1e-6f);

    int count = 0;

    // ---- own cell (1-deep prefetch; ~90% of edges cap-exit here) ----
    {
        const int n = cellCount[cell];         // >=1 (own edge)
        const float4* __restrict__ L = cellList + (size_t)cell * CAPC;
        float4 cur = L[lane];
        for (int base = 0;;) {
            int nb = base + 64;
            bool more = nb < n;
            float4 nxt;
            if (more) nxt = L[nb + lane];
            float dx = ex - cur.x, dy = ey - cur.y, dz = ez - cur.z;
            float d2 = dx*dx + dy*dy + dz*dz;
            bool c = (base + lane < n) && (d2 < d2t);
            count += __popcll(__ballot(c));
            if (count >= CAP) goto done;       // wave-uniform
            if (!more) break;
            cur = nxt; base = nb;
        }
    }

    // ---- survivors: flat chunk list over 26 cells, densest-first ----
    {
        const int dirx = (ix <= 3) ? 1 : -1;
        const int diry = (iy <= 3) ? 1 : -1;
        const int dirz = (iz <= 3) ? 1 : -1;

        int cq = 0, nq = 0, cellq = cell;
        if (lane < 26) {
            int ox = PPAT[lane][0] * dirx;
            int oy = PPAT[lane][1] * diry;
            int oz = PPAT[lane][2] * dirz;
            int x = ix + ox, y = iy + oy, z = iz + oz;
            if (((unsigned)x < (unsigned)GD) & ((unsigned)y < (unsigned)GD) &
                ((unsigned)z < (unsigned)GD)) {
                cellq = cell + oz*64 + oy*8 + ox;
                nq = cellCount[cellq];
                cq = (nq + 63) >> 6;
            }
        }
        int incl = cq;
#pragma unroll
        for (int d = 1; d < 64; d <<= 1) {
            int t = __shfl_up(incl, d, 64);
            if (lane >= d) incl += t;
        }
        const int T = __shfl(incl, 63);        // total chunks (lanes>=26 add 0)
        const int excl = incl - cq;

        if (T == 0) goto done;

        if (T > FLATCAP) {
            // rare exact fallback: simple serial scan, same cells, same order
            for (int q = 0; q < 26; ++q) {
                int ox = PPAT[q][0] * dirx, oy = PPAT[q][1] * diry,
                    oz = PPAT[q][2] * dirz;
                int x = ix + ox, y = iy + oy, z = iz + oz;
                if (((unsigned)x >= (unsigned)GD) | ((unsigned)y >= (unsigned)GD) |
                    ((unsigned)z >= (unsigned)GD)) continue;
                int nc2 = cell + oz*64 + oy*8 + ox;
                int n = cellCount[nc2];
                const float4* __restrict__ L = cellList + (size_t)nc2 * CAPC;
                for (int base = 0; base < n; base += 64) {
                    float4 t4 = L[base + lane];
                    float dx = ex - t4.x, dy = ey - t4.y, dz = ez - t4.z;
                    float d2 = dx*dx + dy*dy + dz*dz;
                    bool c = (base + lane < n) && (d2 < d2t);
                    count += __popcll(__ballot(c));
                    if (count >= CAP) goto done;
                }
            }
            goto done;
        }

        // emit entries: cell(9b)<<14 | chunk(7b)<<7 | nvalid(7b)
        for (int k = 0; k < cq; ++k)
            flatLDS[wave][excl + k] =
                ((unsigned)cellq << 14) | ((unsigned)k << 7)
                | (unsigned)min(64, nq - k*64);
        {
            int pi = T + lane;                 // pads: nvalid=0, own-cell chunk 0
            if (pi < T + 12) flatLDS[wave][pi] = (unsigned)cell << 14;
        }
        asm volatile("s_waitcnt lgkmcnt(0)" ::: "memory"); // same-wave LDS RAW

        const int Tp = (T + 3) & ~3;

#define FADDR(E) (cellList + (size_t)((E) >> 14) * CAPC + (((E) >> 7) & 127) * 64 + lane)
#define PROC(B, EN)                                                        \
        {                                                                  \
            float dx = ex - (B).x, dy = ey - (B).y, dz = ez - (B).z;       \
            float d2 = dx*dx + dy*dy + dz*dz;                              \
            bool c = (lane < (int)((EN) & 127u)) && (d2 < d2t);            \
            count += __popcll(__ballot(c));                                \
            if (count >= CAP) goto done;                                   \
        }

        unsigned e0 = flatLDS[wave][0], e1 = flatLDS[wave][1],
                 e2 = flatLDS[wave][2], e3 = flatLDS[wave][3];
        float4 b0 = *FADDR(e0), b1 = *FADDR(e1), b2 = *FADDR(e2), b3 = *FADDR(e3);
        for (int j = 0;; j += 4) {
            unsigned f0 = flatLDS[wave][j+4], f1 = flatLDS[wave][j+5],
                     f2 = flatLDS[wave][j+6], f3 = flatLDS[wave][j+7];
            float4 n0 = *FADDR(f0), n1 = *FADDR(f1),
                   n2 = *FADDR(f2), n3 = *FADDR(f3);   // issued before compute
            PROC(b0, e0) PROC(b1, e1) PROC(b2, e2) PROC(b3, e3)
            if (j + 4 >= Tp) break;
            e0 = f0; e1 = f1; e2 = f2; e3 = f3;
            b0 = n0; b1 = n1; b2 = n2; b3 = n3;
        }
#undef FADDR
#undef PROC
    }
done:
    if (lane == 0) cnt[e] = count;
}

__global__ __launch_bounds__(1024) void reduce_kernel(
    const int* __restrict__ cnt, const float* __restrict__ probs,
    float* __restrict__ out)
{
    float local = 0.0f;
    for (int f = threadIdx.x; f < F_; f += 1024) {
        // face f's edges in the concatenated [(0,1),(1,2),(2,0)] layout
        float c = (float)(cnt[f] + cnt[F_ + f] + cnt[2*F_ + f]);
        c = fminf(fmaxf(c, 0.0f), 100.0f);
        local += probs[f] * c;
    }
#pragma unroll
    for (int off = 32; off > 0; off >>= 1)
        local += __shfl_down(local, off, 64);
    __shared__ float wsum[16];
    if ((threadIdx.x & 63) == 0) wsum[threadIdx.x >> 6] = local;
    __syncthreads();
    if (threadIdx.x == 0) {
        float t = 0.0f;
#pragma unroll
        for (int w = 0; w < 16; w++) t += wsum[w];
        out[0] = t / (float)F_;
    }
}

extern "C" void kernel_launch(void* const* d_in, const int* in_sizes, int n_in,
                              void* d_out, int out_size, void* d_ws, size_t ws_size,
                              hipStream_t stream)
{
    const float* vertices = (const float*)d_in[0];
    const int*   faces    = (const int*)d_in[1];   // int64 in reference -> int32 on device
    const float* probs    = (const float*)d_in[2];
    float* out = (float*)d_out;

    char* ws = (char*)d_ws;
    float4* C4        = (float4*)ws;
    float4* cellList  = (float4*)(ws + OFF_LIST);
    int*    cellCount = (int*)(ws + OFF_CCNT);
    int*    cnt       = (int*)(ws + OFF_CNT);

    hipMemsetAsync(cellCount, 0, NC * sizeof(int), stream);
    hipLaunchKernelGGL(build_kernel, dim3(E_ / 256), dim3(256), 0, stream,
                       vertices, faces, C4, cellList, cellCount);
    hipLaunchKernelGGL(count_kernel, dim3(E_ / 4), dim3(256), 0, stream,
                       C4, cellList, cellCount, cnt);
    hipLaunchKernelGGL(reduce_kernel, dim3(1), dim3(1024), 0, stream,
                       cnt, probs, out);
}